// Round 4
// baseline (351.860 us; speedup 1.0000x reference)
//
#include <hip/hip_runtime.h>

#define N_NODES 50000
#define N_EDGES 1600000
#define NEG_SLOPE 0.2f
#define LOG2E 1.44269504f

// CSR build parameters: pow2 node buckets
#define NBUCK 98          // ceil(50000/512)
#define BSH 9             // bucket = node >> 9
#define NPB 512
#define CHUNK 6400
#define NBLK 250          // 250*6400 = 1600000

typedef __attribute__((ext_vector_type(8))) short short8;
typedef __attribute__((ext_vector_type(4))) float floatx4;

__device__ __forceinline__ unsigned short f2bf(float f) {
  unsigned u = __float_as_uint(f);
  u += 0x7FFFu + ((u >> 16) & 1);
  return (unsigned short)(u >> 16);
}
__device__ __forceinline__ float bflo(unsigned u) { return __uint_as_float(u << 16); }
__device__ __forceinline__ float bfhi(unsigned u) { return __uint_as_float(u & 0xFFFF0000u); }
__device__ __forceinline__ float fexp2(float x) {
#if __has_builtin(__builtin_amdgcn_exp2f)
  return __builtin_amdgcn_exp2f(x);   // raw v_exp_f32
#else
  return exp2f(x);
#endif
}

// ---- packed bf16 helpers for the aggregation inner loop ----
// RNE-rounded bf16 bits of f, left in bits [31:16] (same rounding as f2bf).
__device__ __forceinline__ unsigned rnebits(float f) {
  unsigned u = __float_as_uint(f);
  return u + 0x7FFFu + ((u >> 16) & 1);
}
// D += dot2(bf16x2 xpk, bf16x2 wpk) with f32 products & accum
__device__ __forceinline__ void dot2acc(float& acc, unsigned xpk, unsigned wpk) {
  asm("v_dot2_f32_bf16 %0, %1, %2, %0" : "+v"(acc) : "v"(xpk), "v"(wpk));
}
// v_perm byte table: bytes 0-3 = S1 (2nd arg), bytes 4-7 = S0 (1st arg).
//   PSEL_LO -> D = {lo16: arg1.lo16, hi16: arg0.lo16}
//   PSEL_HI -> D = {lo16: arg1.hi16, hi16: arg0.hi16}
// Verified by the passing round-2/3 tests: xpk = perm(u1, u0, LO/HI) pairs as
// {edge0, edge1}; wpk built with the same convention matches.
#define PSEL_LO 0x05040100u
#define PSEL_HI 0x07060302u

__device__ __forceinline__ void agg_pair(float* a, float& den, unsigned wpk,
                                         const uint4& u0, const uint4& u1) {
  dot2acc(a[0], __builtin_amdgcn_perm(u1.x, u0.x, PSEL_LO), wpk);
  dot2acc(a[1], __builtin_amdgcn_perm(u1.x, u0.x, PSEL_HI), wpk);
  dot2acc(a[2], __builtin_amdgcn_perm(u1.y, u0.y, PSEL_LO), wpk);
  dot2acc(a[3], __builtin_amdgcn_perm(u1.y, u0.y, PSEL_HI), wpk);
  dot2acc(a[4], __builtin_amdgcn_perm(u1.z, u0.z, PSEL_LO), wpk);
  dot2acc(a[5], __builtin_amdgcn_perm(u1.z, u0.z, PSEL_HI), wpk);
  dot2acc(a[6], __builtin_amdgcn_perm(u1.w, u0.w, PSEL_LO), wpk);
  dot2acc(a[7], __builtin_amdgcn_perm(u1.w, u0.w, PSEL_HI), wpk);
  dot2acc(den, 0x3F803F80u, wpk);  // += bf(w0)*1 + bf(w1)*1 — den matches numerator weights
}

// ---------------- setup: edge histograms + weight prep + x -> bf16 ----------------
__global__ __launch_bounds__(256) void k_setup(
    const int* __restrict__ ei, int* __restrict__ blockhist,
    const float* __restrict__ W_f, const float* __restrict__ W_b,
    const float* __restrict__ W_fu,
    unsigned short* __restrict__ Bt1, unsigned short* __restrict__ Bt2,
    const float* __restrict__ x, unsigned short* __restrict__ Xb16)
{
  const int tid = threadIdx.x;
  if (blockIdx.x >= NBLK + 256) {
    const unsigned gid = (unsigned)(blockIdx.x - (NBLK + 256)) * 256u + tid;
    const unsigned row = gid >> 6, c = (gid & 63) * 4;
    float4 v = *(const float4*)(x + (size_t)row * 256 + c);
    *(ushort4*)(Xb16 + (size_t)row * 256 + c) =
        make_ushort4(f2bf(v.x), f2bf(v.y), f2bf(v.z), f2bf(v.w));
    return;
  }
  if (blockIdx.x >= NBLK) {
    const int k = blockIdx.x - NBLK;
    float w1 = (tid < 128) ? W_f[k * 128 + tid] : W_b[k * 128 + (tid - 128)];
    Bt1[(size_t)tid * 256 + k] = f2bf(w1);
    Bt2[(size_t)tid * 256 + k] = f2bf(W_fu[k * 256 + tid]);
    return;
  }
  __shared__ int hist[2 * NBUCK];
  const int blk = blockIdx.x;
  for (int i = tid; i < 2 * NBUCK; i += 256) hist[i] = 0;
  __syncthreads();
  const int e0 = blk * CHUNK;
  for (int e = e0 + tid; e < e0 + CHUNK; e += 256) {
    int s = ei[e];
    int d = ei[N_EDGES + e];
    atomicAdd(&hist[d >> BSH], 1);
    atomicAdd(&hist[NBUCK + (s >> BSH)], 1);
  }
  __syncthreads();
  for (int i = tid; i < 2 * NBUCK; i += 256)
    blockhist[i * NBLK + blk] = hist[i];
}

// ---------------- per-bucket scan over blocks ----------------
__global__ __launch_bounds__(256) void k_rowscan(const int* __restrict__ blockhist,
                                                 int* __restrict__ blockoffs, int* __restrict__ bucktotal) {
  const int i = blockIdx.x;
  const int t = threadIdx.x;
  __shared__ int s[256];
  int v = (t < NBLK) ? blockhist[i * NBLK + t] : 0;
  s[t] = v;
  __syncthreads();
  for (int off = 1; off < 256; off <<= 1) {
    int u = (t >= off) ? s[t - off] : 0;
    __syncthreads();
    s[t] += u;
    __syncthreads();
  }
  if (t < NBLK) blockoffs[i * NBLK + t] = s[t] - v;
  if (t == 255) bucktotal[i] = s[255];
}

// ---------------- scan bucket totals ----------------
__global__ __launch_bounds__(256) void k_buckscan(const int* __restrict__ bucktotal,
                                                  int* __restrict__ buckbase, int* rpf, int* rpb) {
  __shared__ int s[256];
  const int t = threadIdx.x;
  int v = (t < 2 * NBUCK) ? bucktotal[t] : 0;
  s[t] = v;
  __syncthreads();
  for (int off = 1; off < 256; off <<= 1) {
    int u = (t >= off) ? s[t - off] : 0;
    __syncthreads();
    s[t] += u;
    __syncthreads();
  }
  if (t < 2 * NBUCK) {
    const int dir = (t >= NBUCK) ? 1 : 0;
    const int b = t - dir * NBUCK;
    const int sub = dir ? s[NBUCK - 1] : 0;
    buckbase[dir * (NBUCK + 1) + b] = s[t] - v - sub;
    if (b == NBUCK - 1) buckbase[dir * (NBUCK + 1) + NBUCK] = s[t] - sub;
  }
  if (t == 0) { rpf[N_NODES] = N_EDGES + N_NODES; rpb[N_NODES] = N_EDGES + N_NODES; }
}

// ---------------- MFMA GEMM body (shared by fused + standalone kernels) ----------------
#define LDA 40

__device__ __forceinline__ void mm_body(
    const unsigned short* __restrict__ A, int M,
    const unsigned short* __restrict__ Bt,
    unsigned short* __restrict__ D0, unsigned short* __restrict__ D1,
    float* __restrict__ Df, int mode,
    const float* __restrict__ bias, const float* __restrict__ gamma,
    const float* __restrict__ beta, const float* __restrict__ mean,
    const float* __restrict__ var,
    int m0, int col0, unsigned short* As, unsigned short* Bs)
{
  const int tid = threadIdx.x;
  const int wave = tid >> 6, lane = tid & 63;
  const int wm = wave >> 1, wn = wave & 1;
  const int lm = lane & 15, quad = lane >> 4;

  floatx4 acc[4][4];
#pragma unroll
  for (int i = 0; i < 4; ++i)
#pragma unroll
    for (int j = 0; j < 4; ++j) acc[i][j] = (floatx4){0.f, 0.f, 0.f, 0.f};

  for (int it = 0; it < 8; ++it) {
    const int kk0 = it * 32;
    __syncthreads();
#pragma unroll
    for (int q = 0; q < 2; ++q) {
      int idx = q * 256 + tid;
      int r = idx >> 2, c8 = (idx & 3) * 8;
      ulonglong2 z; z.x = 0; z.y = 0;
      if (m0 + r < M) z = *(const ulonglong2*)(A + (size_t)(m0 + r) * 256 + kk0 + c8);
      *(ulonglong2*)&As[r * LDA + c8] = z;
    }
#pragma unroll
    for (int q = 0; q < 2; ++q) {
      int idx = q * 256 + tid;
      int nc = idx >> 2, c8 = (idx & 3) * 8;
      ulonglong2 z = *(const ulonglong2*)(Bt + (size_t)(col0 + nc) * 256 + kk0 + c8);
      *(ulonglong2*)&Bs[nc * LDA + c8] = z;
    }
    __syncthreads();
    short8 a[4], b[4];
#pragma unroll
    for (int i = 0; i < 4; ++i)
      a[i] = *(const short8*)&As[(wm * 64 + i * 16 + lm) * LDA + quad * 8];
#pragma unroll
    for (int j = 0; j < 4; ++j)
      b[j] = *(const short8*)&Bs[(wn * 64 + j * 16 + lm) * LDA + quad * 8];
#pragma unroll
    for (int i = 0; i < 4; ++i)
#pragma unroll
      for (int j = 0; j < 4; ++j)
        acc[i][j] = __builtin_amdgcn_mfma_f32_16x16x32_bf16(a[i], b[j], acc[i][j], 0, 0, 0);
  }

  if (mode == 0) {
    unsigned short* C = (col0 >= 128) ? D1 : D0;
#pragma unroll
    for (int i = 0; i < 4; ++i) {
#pragma unroll
      for (int j = 0; j < 4; ++j) {
        int lc = (wn * 64 + j * 16 + lm);
#pragma unroll
        for (int reg = 0; reg < 4; ++reg) {
          int gr = m0 + wm * 64 + i * 16 + quad * 4 + reg;
          if (gr < M) C[(size_t)gr * 128 + lc] = f2bf(acc[i][j][reg]);
        }
      }
    }
  } else {
#pragma unroll
    for (int j = 0; j < 4; ++j) {
      int gc = col0 + wn * 64 + j * 16 + lm;
      float bi = bias[gc], mu = mean[gc], iv = rsqrtf(var[gc] + 1e-5f);
      float ga = gamma[gc], be = beta[gc];
#pragma unroll
      for (int i = 0; i < 4; ++i) {
#pragma unroll
        for (int reg = 0; reg < 4; ++reg) {
          int gr = m0 + wm * 64 + i * 16 + quad * 4 + reg;
          if (gr < M) {
            float v = acc[i][j][reg] + bi;
            v = (v - mu) * iv * ga + be;
            Df[(size_t)gr * 256 + gc] = fmaxf(v, 0.f);
          }
        }
      }
    }
  }
}

// ---------------- fused: edge scatter-to-staging + projection GEMM ----------------
__global__ __launch_bounds__(256) void k_stage_mm(
    const int* __restrict__ ei, const int* __restrict__ blockoffs,
    const int* __restrict__ buckbase, unsigned* __restrict__ staging,
    const unsigned short* __restrict__ Xb16, const unsigned short* __restrict__ Bt1,
    unsigned short* __restrict__ Xf, unsigned short* __restrict__ Xb)
{
  __shared__ union {
    int cur[2 * NBUCK];
    struct { unsigned short As[128 * LDA]; unsigned short Bs[128 * LDA]; } mm;
  } sm;
  const int tid = threadIdx.x;
  if (blockIdx.x < NBLK) {
    const int blk = blockIdx.x;
    for (int i = tid; i < 2 * NBUCK; i += 256) {
      int dir = (i >= NBUCK) ? 1 : 0;
      int b = i - dir * NBUCK;
      sm.cur[i] = blockoffs[i * NBLK + blk] + buckbase[dir * (NBUCK + 1) + b];
    }
    __syncthreads();
    unsigned* st0 = staging;
    unsigned* st1 = staging + N_EDGES;
    const int e0 = blk * CHUNK;
    for (int e = e0 + tid; e < e0 + CHUNK; e += 256) {
      int s = ei[e];
      int d = ei[N_EDGES + e];
      int p = atomicAdd(&sm.cur[d >> BSH], 1);
      st0[p] = ((unsigned)(d & (NPB - 1)) << 16) | (unsigned)s;
      int q = atomicAdd(&sm.cur[NBUCK + (s >> BSH)], 1);
      st1[q] = ((unsigned)(s & (NPB - 1)) << 16) | (unsigned)d;
    }
    return;
  }
  const int bid = blockIdx.x - NBLK;
  mm_body(Xb16, N_NODES, Bt1, Xf, Xb, nullptr, 0,
          nullptr, nullptr, nullptr, nullptr, nullptr,
          (bid >> 1) * 128, (bid & 1) * 128, sm.mm.As, sm.mm.Bs);
}

// ---------------- fused: bin-within-bucket + attention score dots ----------------
__global__ __launch_bounds__(512) void k_bin_scores(
    const unsigned* __restrict__ staging, const int* __restrict__ buckbase,
    int* __restrict__ rpf, int* __restrict__ rpb,
    int* __restrict__ adjf, int* __restrict__ adjb,
    const unsigned short* __restrict__ Xf, const unsigned short* __restrict__ Xb,
    const float* __restrict__ asf, const float* __restrict__ adf,
    const float* __restrict__ asb, const float* __restrict__ adb,
    float* __restrict__ ALf, float* __restrict__ ARf,
    float* __restrict__ ALb, float* __restrict__ ARb)
{
  const int tid = threadIdx.x;
  if (blockIdx.x < 2 * NBUCK) {
    const int dir = (blockIdx.x >= NBUCK) ? 1 : 0;
    const int b = blockIdx.x - dir * NBUCK;
    const int node0 = b << BSH;
    const int nn = min(NPB, N_NODES - node0);
    const unsigned* st = staging + (size_t)dir * N_EDGES;
    int* rp  = dir ? rpb : rpf;
    int* adj = dir ? adjb : adjf;
    const int beg = buckbase[dir * (NBUCK + 1) + b];
    const int end = buckbase[dir * (NBUCK + 1) + b + 1];

    __shared__ int cnt[NPB];
    __shared__ int wpart[8];
    cnt[tid] = 0;
    __syncthreads();
    for (int jj = beg + tid; jj < end; jj += 512)
      atomicAdd(&cnt[st[jj] >> 16], 1);
    __syncthreads();
    const int deg1 = (tid < nn) ? cnt[tid] + 1 : 0;   // +1 self loop
    int v = deg1;
    const int wl = tid & 63;
#pragma unroll
    for (int off = 1; off < 64; off <<= 1) {
      int u = __shfl_up(v, off, 64);
      if (wl >= off) v += u;
    }
    if (wl == 63) wpart[tid >> 6] = v;
    __syncthreads();
    int pre = 0;
#pragma unroll
    for (int w = 0; w < 7; ++w)
      if (w < (tid >> 6)) pre += wpart[w];
    const int excl = v + pre - deg1;
    if (tid < nn) {
      int r = beg + node0 + excl;
      rp[node0 + tid] = r;
      adj[r] = node0 + tid;                           // self loop first
      cnt[tid] = r + 1;
    }
    __syncthreads();
    for (int jj = beg + tid; jj < end; jj += 512) {
      unsigned rec = st[jj];
      int p = atomicAdd(&cnt[rec >> 16], 1);
      adj[p] = (int)(rec & 0xFFFFu);
    }
    return;
  }
  // ---- scores: 8 nodes per block (one wave each), outputs pre-scaled by log2e ----
  const int wave = tid >> 6, lane = tid & 63;
  const int n = (blockIdx.x - 2 * NBUCK) * 8 + wave;
  const int hh = lane >> 5;
  const int c = lane & 31;
  float v0 = bflo((unsigned)Xf[(size_t)n * 128 + lane]);
  float v1 = bflo((unsigned)Xf[(size_t)n * 128 + 64 + lane]);
  float v2 = bflo((unsigned)Xb[(size_t)n * 128 + lane]);
  float v3 = bflo((unsigned)Xb[(size_t)n * 128 + 64 + lane]);
  float s0 = v0 * asf[hh * 32 + c],       d0 = v0 * adf[hh * 32 + c];
  float s1 = v1 * asf[(2 + hh) * 32 + c], d1 = v1 * adf[(2 + hh) * 32 + c];
  float s2 = v2 * asb[hh * 32 + c],       d2 = v2 * adb[hh * 32 + c];
  float s3 = v3 * asb[(2 + hh) * 32 + c], d3 = v3 * adb[(2 + hh) * 32 + c];
#pragma unroll
  for (int off = 16; off > 0; off >>= 1) {
    s0 += __shfl_xor(s0, off, 32); d0 += __shfl_xor(d0, off, 32);
    s1 += __shfl_xor(s1, off, 32); d1 += __shfl_xor(d1, off, 32);
    s2 += __shfl_xor(s2, off, 32); d2 += __shfl_xor(d2, off, 32);
    s3 += __shfl_xor(s3, off, 32); d3 += __shfl_xor(d3, off, 32);
  }
  if (c == 0) {
    ALf[n * 4 + hh] = s0 * LOG2E;     ARf[n * 4 + hh] = d0 * LOG2E;
    ALf[n * 4 + 2 + hh] = s1 * LOG2E; ARf[n * 4 + 2 + hh] = d1 * LOG2E;
    ALb[n * 4 + hh] = s2 * LOG2E;     ARb[n * 4 + hh] = d2 * LOG2E;
    ALb[n * 4 + 2 + hh] = s3 * LOG2E; ARb[n * 4 + 2 + hh] = d3 * LOG2E;
  }
}

// ---------------- fused softmax + aggregation (v4: LDS batch + depth-2 pipeline) ------
// Per 64-edge window: batch phase (lane=edge) computes packed per-head bf16 weights
// into wave-private LDS (slots padded to 72 with w=0 so the pipelined inner loop can
// prefetch unconditionally). Accumulate phase: depth-2 software pipeline — iteration
// k+1's X-rows + weights are issued before iteration k is consumed, keeping 4+ X-row
// gathers in flight per wave to cover L2/LLC latency.
__global__ __launch_bounds__(256) void k_agg(
    const uint4* __restrict__ Xf, const uint4* __restrict__ Xb,
    const int* __restrict__ rpf, const int* __restrict__ adjf,
    const int* __restrict__ rpb, const int* __restrict__ adjb,
    const float* __restrict__ ALf, const float* __restrict__ ARf,
    const float* __restrict__ ALb, const float* __restrict__ ARb,
    const float* __restrict__ bf, const float* __restrict__ bb,
    unsigned* __restrict__ H16)
{
  __shared__ int      sNB[4][72];
  __shared__ unsigned sW[4][72][2];
  const int dir = blockIdx.y;
  const int wv = threadIdx.x >> 6;
  const int n = blockIdx.x * 4 + wv;
  const uint4* X = dir ? Xb : Xf;
  const int* rp  = dir ? rpb : rpf;
  const int* adj = dir ? adjb : adjf;
  const float* AL = dir ? ALb : ALf;
  const float* AR = dir ? ARb : ARf;
  const float* bias = dir ? bb : bf;
  const int lane = threadIdx.x & 63;
  const int sg = lane >> 4;           // sub-group = which pair-slot of the octet
  const unsigned l = (unsigned)(lane & 15);
  const unsigned h = l >> 2;          // head for channels 8l..8l+7
  const unsigned sel = (h & 1) ? PSEL_HI : PSEL_LO;  // pick this head's half of W[h>>1]
  const float4 ar4 = *(const float4*)(AR + ((size_t)(unsigned)n << 2));
  const int beg = rp[n], end = rp[n + 1];
  const int cntE = end - beg;

  float a[8] = {0.f, 0.f, 0.f, 0.f, 0.f, 0.f, 0.f, 0.f};
  float den = 0.f;

  for (int wb = 0; wb < cntE; wb += 64) {
    const int wcnt = min(cntE - wb, 64);
    // ---- batch phase: one edge per lane -> weights + nb into wave-private LDS ----
    const bool valid = lane < wcnt;
    const int eidx = beg + (valid ? wb + lane : 0);   // beg always valid (self loop)
    const int nb = adj[eidx];
    const float4 alv = *(const float4*)(AL + ((size_t)(unsigned)nb << 2));
    float s0 = alv.x + ar4.x, s1 = alv.y + ar4.y;
    float s2 = alv.z + ar4.z, s3 = alv.w + ar4.w;
    float w0 = fexp2(fmaxf(s0, s0 * NEG_SLOPE));
    float w1 = fexp2(fmaxf(s1, s1 * NEG_SLOPE));
    float w2 = fexp2(fmaxf(s2, s2 * NEG_SLOPE));
    float w3 = fexp2(fmaxf(s3, s3 * NEG_SLOPE));
    // W0 = {lo: bf(w_h0), hi: bf(w_h1)}, W1 = {lo: bf(w_h2), hi: bf(w_h3)}
    unsigned W0 = __builtin_amdgcn_perm(rnebits(w1), rnebits(w0), PSEL_HI);
    unsigned W1 = __builtin_amdgcn_perm(rnebits(w3), rnebits(w2), PSEL_HI);
    if (!valid) { W0 = 0u; W1 = 0u; }   // OOB slots contribute 0 (replaces remainder path)
    sNB[wv][lane] = nb;
    sW[wv][lane][0] = W0;
    sW[wv][lane][1] = W1;
    if (lane < 8) {                     // pad slots 64..71: valid node, zero weight
      sNB[wv][64 + lane] = nb;
      sW[wv][64 + lane][0] = 0u;
      sW[wv][64 + lane][1] = 0u;
    }
    __builtin_amdgcn_wave_barrier();    // intra-wave LDS write->read ordering fence
    // ---- accumulate phase: depth-2 pipelined round-robin pairs ----
    const int K = (wcnt + 7) >> 3;
    {
      const int p0 = 2 * sg;
      int nb0 = sNB[wv][p0];
      int nb1 = sNB[wv][p0 + 1];
      unsigned We0 = sW[wv][p0][h >> 1];
      unsigned We1 = sW[wv][p0 + 1][h >> 1];
      uint4 c0 = X[((unsigned)nb0 << 4) | l];
      uint4 c1 = X[((unsigned)nb1 << 4) | l];
      unsigned wcur = __builtin_amdgcn_perm(We1, We0, sel);
#pragma unroll 2
      for (int k = 0; k < K; ++k) {
        const int pn = 8 * (k + 1) + 2 * sg;          // ≤ 71: covered by pad slots
        const int m0 = sNB[wv][pn];
        const int m1 = sNB[wv][pn + 1];
        const unsigned Vn0 = sW[wv][pn][h >> 1];
        const unsigned Vn1 = sW[wv][pn + 1][h >> 1];
        uint4 n0 = X[((unsigned)m0 << 4) | l];        // issue k+1 before consuming k
        uint4 n1 = X[((unsigned)m1 << 4) | l];
        const unsigned wnext = __builtin_amdgcn_perm(Vn1, Vn0, sel);
        agg_pair(a, den, wcur, c0, c1);
        c0 = n0; c1 = n1; wcur = wnext;
      }
    }
    __builtin_amdgcn_wave_barrier();    // keep next window's writes below these reads
  }
  // reduce across the 4 sub-groups (xor 16, then 32)
#pragma unroll
  for (int off = 16; off <= 32; off <<= 1) {
#pragma unroll
    for (int k = 0; k < 8; ++k) a[k] += __shfl_xor(a[k], off);
    den += __shfl_xor(den, off);
  }
  if (lane < 16) {
    float inv = 1.f / (den + 1e-16f);
    float4 b0 = *(const float4*)(bias + 8 * l);
    float4 b1 = *(const float4*)(bias + 8 * l + 4);
    float v0 = a[0] * inv + b0.x, v1 = a[1] * inv + b0.y;
    float v2 = a[2] * inv + b0.z, v3 = a[3] * inv + b0.w;
    float v4 = a[4] * inv + b1.x, v5 = a[5] * inv + b1.y;
    float v6 = a[6] * inv + b1.z, v7 = a[7] * inv + b1.w;
    uint4 hw;
    hw.x = ((unsigned)f2bf(v1) << 16) | f2bf(v0);
    hw.y = ((unsigned)f2bf(v3) << 16) | f2bf(v2);
    hw.z = ((unsigned)f2bf(v5) << 16) | f2bf(v4);
    hw.w = ((unsigned)f2bf(v7) << 16) | f2bf(v6);
    *(uint4*)(H16 + (unsigned)n * 128u + (unsigned)dir * 64u + 4u * l) = hw;
  }
}

// ---------------- standalone fusion GEMM (mode 1) ----------------
__global__ __launch_bounds__(256) void k_mm2(
    const unsigned short* __restrict__ A, const unsigned short* __restrict__ Bt,
    float* __restrict__ Df,
    const float* __restrict__ bias, const float* __restrict__ gamma,
    const float* __restrict__ beta, const float* __restrict__ mean,
    const float* __restrict__ var)
{
  __shared__ __align__(16) unsigned short As[128 * LDA];
  __shared__ __align__(16) unsigned short Bs[128 * LDA];
  mm_body(A, N_NODES, Bt, nullptr, nullptr, Df, 1,
          bias, gamma, beta, mean, var,
          blockIdx.x * 128, blockIdx.y * 128, As, Bs);
}

// ---------------- launch ----------------

extern "C" void kernel_launch(void* const* d_in, const int* in_sizes, int n_in,
                              void* d_out, int out_size, void* d_ws, size_t ws_size,
                              hipStream_t stream) {
  const float* x    = (const float*)d_in[0];
  const int*   ei   = (const int*)d_in[1];
  const float* W_f  = (const float*)d_in[2];
  const float* asf  = (const float*)d_in[3];
  const float* adf  = (const float*)d_in[4];
  const float* b_f  = (const float*)d_in[5];
  const float* W_b  = (const float*)d_in[6];
  const float* asb  = (const float*)d_in[7];
  const float* adb  = (const float*)d_in[8];
  const float* b_b  = (const float*)d_in[9];
  const float* W_fu = (const float*)d_in[10];
  const float* b_fu = (const float*)d_in[11];
  const float* gam  = (const float*)d_in[12];
  const float* bet  = (const float*)d_in[13];
  const float* mean = (const float*)d_in[14];
  const float* var  = (const float*)d_in[15];
  float* out = (float*)d_out;

  char* base = (char*)d_ws;
  size_t off = 0;
  auto alloc = [&](size_t bytes) {
    void* p = base + off;
    off = (off + bytes + 255) & ~(size_t)255;
    return p;
  };
  // Xb16 (mm1 input) and H16 (agg output / mm2 input) live at disjoint times -> share
  unsigned short* Xb16 = (unsigned short*)alloc((size_t)N_NODES * 256 * 2);
  unsigned* H16        = (unsigned*)Xb16;
  unsigned short* Xf   = (unsigned short*)alloc((size_t)N_NODES * 128 * 2);
  unsigned short* Xb   = (unsigned short*)alloc((size_t)N_NODES * 128 * 2);
  unsigned short* Bt1  = (unsigned short*)alloc((size_t)256 * 256 * 2);
  unsigned short* Bt2  = (unsigned short*)alloc((size_t)256 * 256 * 2);
  float* ALf  = (float*)alloc((size_t)N_NODES * 4 * 4);
  float* ARf  = (float*)alloc((size_t)N_NODES * 4 * 4);
  float* ALb  = (float*)alloc((size_t)N_NODES * 4 * 4);
  float* ARb  = (float*)alloc((size_t)N_NODES * 4 * 4);
  int* rpf    = (int*)alloc((size_t)(N_NODES + 1) * 4);
  int* rpb    = (int*)alloc((size_t)(N_NODES + 1) * 4);
  int* adjf   = (int*)alloc((size_t)(N_EDGES + N_NODES) * 4);
  int* adjb   = (int*)alloc((size_t)(N_EDGES + N_NODES) * 4);
  int* blockhist = (int*)alloc((size_t)2 * NBUCK * NBLK * 4);
  int* blockoffs = (int*)alloc((size_t)2 * NBUCK * NBLK * 4);
  int* bucktotal = (int*)alloc((size_t)2 * NBUCK * 4);
  int* buckbase  = (int*)alloc((size_t)2 * (NBUCK + 1) * 4);
  unsigned* staging = (unsigned*)alloc((size_t)2 * N_EDGES * 4);
  (void)ws_size; (void)in_sizes; (void)n_in; (void)out_size;

  const int XB = (N_NODES * 64) / 256;            // 12500
  const int MB = (N_NODES + 127) / 128;           // 391

  k_setup<<<NBLK + 256 + XB, 256, 0, stream>>>(ei, blockhist, W_f, W_b, W_fu,
                                               Bt1, Bt2, x, Xb16);
  k_rowscan<<<2 * NBUCK, 256, 0, stream>>>(blockhist, blockoffs, bucktotal);
  k_buckscan<<<1, 256, 0, stream>>>(bucktotal, buckbase, rpf, rpb);
  // fused: edge staging (chain A) + projection GEMM (chain B)
  k_stage_mm<<<NBLK + MB * 2, 256, 0, stream>>>(ei, blockoffs, buckbase, staging,
                                                Xb16, Bt1, Xf, Xb);
  // fused: CSR binning (chain A) + attention scores (chain B)
  k_bin_scores<<<2 * NBUCK + N_NODES / 8, 512, 0, stream>>>(
      staging, buckbase, rpf, rpb, adjf, adjb,
      Xf, Xb, asf, adf, asb, adb, ALf, ARf, ALb, ARb);
  k_agg<<<dim3(N_NODES / 4, 2), 256, 0, stream>>>((const uint4*)Xf, (const uint4*)Xb,
                                                  rpf, adjf, rpb, adjb,
                                                  ALf, ARf, ALb, ARb, b_f, b_b, H16);
  k_mm2<<<dim3(MB, 2), 256, 0, stream>>>((const unsigned short*)H16, Bt2, out,
                                         b_fu, gam, bet, mean, var);
}

// Round 5
// 348.478 us; speedup vs baseline: 1.0097x; 1.0097x over previous
//
#include <hip/hip_runtime.h>

#define N_NODES 50000
#define N_EDGES 1600000
#define NEG_SLOPE 0.2f
#define LOG2E 1.44269504f

// CSR build parameters: pow2 node buckets
#define NBUCK 98          // ceil(50000/512)
#define BSH 9             // bucket = node >> 9
#define NPB 512
#define CHUNK 6400
#define NBLK 250          // 250*6400 = 1600000

// source-range grouping for cache-blocked sweep (k_agg locality)
#define NGRP 16           // 16 groups of 4096 source IDs (~1.05 MB of X rows each)
#define GSH 12            // group = src >> 12
#define GPAD 17           // padded stride (odd) -> conflict-free LDS counters

typedef __attribute__((ext_vector_type(8))) short short8;
typedef __attribute__((ext_vector_type(4))) float floatx4;

__device__ __forceinline__ unsigned short f2bf(float f) {
  unsigned u = __float_as_uint(f);
  u += 0x7FFFu + ((u >> 16) & 1);
  return (unsigned short)(u >> 16);
}
__device__ __forceinline__ float bflo(unsigned u) { return __uint_as_float(u << 16); }
__device__ __forceinline__ float bfhi(unsigned u) { return __uint_as_float(u & 0xFFFF0000u); }
__device__ __forceinline__ float fexp2(float x) {
#if __has_builtin(__builtin_amdgcn_exp2f)
  return __builtin_amdgcn_exp2f(x);   // raw v_exp_f32
#else
  return exp2f(x);
#endif
}

// ---- packed bf16 helpers for the aggregation inner loop ----
// RNE-rounded bf16 bits of f, left in bits [31:16] (same rounding as f2bf).
__device__ __forceinline__ unsigned rnebits(float f) {
  unsigned u = __float_as_uint(f);
  return u + 0x7FFFu + ((u >> 16) & 1);
}
// D += dot2(bf16x2 xpk, bf16x2 wpk) with f32 products & accum
__device__ __forceinline__ void dot2acc(float& acc, unsigned xpk, unsigned wpk) {
  asm("v_dot2_f32_bf16 %0, %1, %2, %0" : "+v"(acc) : "v"(xpk), "v"(wpk));
}
// v_perm byte table: bytes 0-3 = S1 (2nd arg), bytes 4-7 = S0 (1st arg).
//   PSEL_LO -> D = {lo16: arg1.lo16, hi16: arg0.lo16}
//   PSEL_HI -> D = {lo16: arg1.hi16, hi16: arg0.hi16}
// Verified by the passing round-2/3/4 tests: xpk = perm(u1, u0, LO/HI) pairs as
// {edge0, edge1}; wpk built with the same convention matches.
#define PSEL_LO 0x05040100u
#define PSEL_HI 0x07060302u

__device__ __forceinline__ void agg_pair(float* a, float& den, unsigned wpk,
                                         const uint4& u0, const uint4& u1) {
  dot2acc(a[0], __builtin_amdgcn_perm(u1.x, u0.x, PSEL_LO), wpk);
  dot2acc(a[1], __builtin_amdgcn_perm(u1.x, u0.x, PSEL_HI), wpk);
  dot2acc(a[2], __builtin_amdgcn_perm(u1.y, u0.y, PSEL_LO), wpk);
  dot2acc(a[3], __builtin_amdgcn_perm(u1.y, u0.y, PSEL_HI), wpk);
  dot2acc(a[4], __builtin_amdgcn_perm(u1.z, u0.z, PSEL_LO), wpk);
  dot2acc(a[5], __builtin_amdgcn_perm(u1.z, u0.z, PSEL_HI), wpk);
  dot2acc(a[6], __builtin_amdgcn_perm(u1.w, u0.w, PSEL_LO), wpk);
  dot2acc(a[7], __builtin_amdgcn_perm(u1.w, u0.w, PSEL_HI), wpk);
  dot2acc(den, 0x3F803F80u, wpk);  // += bf(w0)*1 + bf(w1)*1 — den matches numerator weights
}

// ---------------- setup: edge histograms + weight prep + x -> bf16 ----------------
__global__ __launch_bounds__(256) void k_setup(
    const int* __restrict__ ei, int* __restrict__ blockhist,
    const float* __restrict__ W_f, const float* __restrict__ W_b,
    const float* __restrict__ W_fu,
    unsigned short* __restrict__ Bt1, unsigned short* __restrict__ Bt2,
    const float* __restrict__ x, unsigned short* __restrict__ Xb16)
{
  const int tid = threadIdx.x;
  if (blockIdx.x >= NBLK + 256) {
    const unsigned gid = (unsigned)(blockIdx.x - (NBLK + 256)) * 256u + tid;
    const unsigned row = gid >> 6, c = (gid & 63) * 4;
    float4 v = *(const float4*)(x + (size_t)row * 256 + c);
    *(ushort4*)(Xb16 + (size_t)row * 256 + c) =
        make_ushort4(f2bf(v.x), f2bf(v.y), f2bf(v.z), f2bf(v.w));
    return;
  }
  if (blockIdx.x >= NBLK) {
    const int k = blockIdx.x - NBLK;
    float w1 = (tid < 128) ? W_f[k * 128 + tid] : W_b[k * 128 + (tid - 128)];
    Bt1[(size_t)tid * 256 + k] = f2bf(w1);
    Bt2[(size_t)tid * 256 + k] = f2bf(W_fu[k * 256 + tid]);
    return;
  }
  __shared__ int hist[2 * NBUCK];
  const int blk = blockIdx.x;
  for (int i = tid; i < 2 * NBUCK; i += 256) hist[i] = 0;
  __syncthreads();
  const int e0 = blk * CHUNK;
  for (int e = e0 + tid; e < e0 + CHUNK; e += 256) {
    int s = ei[e];
    int d = ei[N_EDGES + e];
    atomicAdd(&hist[d >> BSH], 1);
    atomicAdd(&hist[NBUCK + (s >> BSH)], 1);
  }
  __syncthreads();
  for (int i = tid; i < 2 * NBUCK; i += 256)
    blockhist[i * NBLK + blk] = hist[i];
}

// ---------------- per-bucket scan over blocks ----------------
__global__ __launch_bounds__(256) void k_rowscan(const int* __restrict__ blockhist,
                                                 int* __restrict__ blockoffs, int* __restrict__ bucktotal) {
  const int i = blockIdx.x;
  const int t = threadIdx.x;
  __shared__ int s[256];
  int v = (t < NBLK) ? blockhist[i * NBLK + t] : 0;
  s[t] = v;
  __syncthreads();
  for (int off = 1; off < 256; off <<= 1) {
    int u = (t >= off) ? s[t - off] : 0;
    __syncthreads();
    s[t] += u;
    __syncthreads();
  }
  if (t < NBLK) blockoffs[i * NBLK + t] = s[t] - v;
  if (t == 255) bucktotal[i] = s[255];
}

// ---------------- scan bucket totals ----------------
__global__ __launch_bounds__(256) void k_buckscan(const int* __restrict__ bucktotal,
                                                  int* __restrict__ buckbase, int* rpf, int* rpb) {
  __shared__ int s[256];
  const int t = threadIdx.x;
  int v = (t < 2 * NBUCK) ? bucktotal[t] : 0;
  s[t] = v;
  __syncthreads();
  for (int off = 1; off < 256; off <<= 1) {
    int u = (t >= off) ? s[t - off] : 0;
    __syncthreads();
    s[t] += u;
    __syncthreads();
  }
  if (t < 2 * NBUCK) {
    const int dir = (t >= NBUCK) ? 1 : 0;
    const int b = t - dir * NBUCK;
    const int sub = dir ? s[NBUCK - 1] : 0;
    buckbase[dir * (NBUCK + 1) + b] = s[t] - v - sub;
    if (b == NBUCK - 1) buckbase[dir * (NBUCK + 1) + NBUCK] = s[t] - sub;
  }
  if (t == 0) { rpf[N_NODES] = N_EDGES + N_NODES; rpb[N_NODES] = N_EDGES + N_NODES; }
}

// ---------------- MFMA GEMM body (shared by fused + standalone kernels) ----------------
#define LDA 40

__device__ __forceinline__ void mm_body(
    const unsigned short* __restrict__ A, int M,
    const unsigned short* __restrict__ Bt,
    unsigned short* __restrict__ D0, unsigned short* __restrict__ D1,
    float* __restrict__ Df, int mode,
    const float* __restrict__ bias, const float* __restrict__ gamma,
    const float* __restrict__ beta, const float* __restrict__ mean,
    const float* __restrict__ var,
    int m0, int col0, unsigned short* As, unsigned short* Bs)
{
  const int tid = threadIdx.x;
  const int wave = tid >> 6, lane = tid & 63;
  const int wm = wave >> 1, wn = wave & 1;
  const int lm = lane & 15, quad = lane >> 4;

  floatx4 acc[4][4];
#pragma unroll
  for (int i = 0; i < 4; ++i)
#pragma unroll
    for (int j = 0; j < 4; ++j) acc[i][j] = (floatx4){0.f, 0.f, 0.f, 0.f};

  for (int it = 0; it < 8; ++it) {
    const int kk0 = it * 32;
    __syncthreads();
#pragma unroll
    for (int q = 0; q < 2; ++q) {
      int idx = q * 256 + tid;
      int r = idx >> 2, c8 = (idx & 3) * 8;
      ulonglong2 z; z.x = 0; z.y = 0;
      if (m0 + r < M) z = *(const ulonglong2*)(A + (size_t)(m0 + r) * 256 + kk0 + c8);
      *(ulonglong2*)&As[r * LDA + c8] = z;
    }
#pragma unroll
    for (int q = 0; q < 2; ++q) {
      int idx = q * 256 + tid;
      int nc = idx >> 2, c8 = (idx & 3) * 8;
      ulonglong2 z = *(const ulonglong2*)(Bt + (size_t)(col0 + nc) * 256 + kk0 + c8);
      *(ulonglong2*)&Bs[nc * LDA + c8] = z;
    }
    __syncthreads();
    short8 a[4], b[4];
#pragma unroll
    for (int i = 0; i < 4; ++i)
      a[i] = *(const short8*)&As[(wm * 64 + i * 16 + lm) * LDA + quad * 8];
#pragma unroll
    for (int j = 0; j < 4; ++j)
      b[j] = *(const short8*)&Bs[(wn * 64 + j * 16 + lm) * LDA + quad * 8];
#pragma unroll
    for (int i = 0; i < 4; ++i)
#pragma unroll
      for (int j = 0; j < 4; ++j)
        acc[i][j] = __builtin_amdgcn_mfma_f32_16x16x32_bf16(a[i], b[j], acc[i][j], 0, 0, 0);
  }

  if (mode == 0) {
    unsigned short* C = (col0 >= 128) ? D1 : D0;
#pragma unroll
    for (int i = 0; i < 4; ++i) {
#pragma unroll
      for (int j = 0; j < 4; ++j) {
        int lc = (wn * 64 + j * 16 + lm);
#pragma unroll
        for (int reg = 0; reg < 4; ++reg) {
          int gr = m0 + wm * 64 + i * 16 + quad * 4 + reg;
          if (gr < M) C[(size_t)gr * 128 + lc] = f2bf(acc[i][j][reg]);
        }
      }
    }
  } else {
#pragma unroll
    for (int j = 0; j < 4; ++j) {
      int gc = col0 + wn * 64 + j * 16 + lm;
      float bi = bias[gc], mu = mean[gc], iv = rsqrtf(var[gc] + 1e-5f);
      float ga = gamma[gc], be = beta[gc];
#pragma unroll
      for (int i = 0; i < 4; ++i) {
#pragma unroll
        for (int reg = 0; reg < 4; ++reg) {
          int gr = m0 + wm * 64 + i * 16 + quad * 4 + reg;
          if (gr < M) {
            float v = acc[i][j][reg] + bi;
            v = (v - mu) * iv * ga + be;
            Df[(size_t)gr * 256 + gc] = fmaxf(v, 0.f);
          }
        }
      }
    }
  }
}

// ---------------- fused: edge scatter-to-staging + projection GEMM ----------------
__global__ __launch_bounds__(256) void k_stage_mm(
    const int* __restrict__ ei, const int* __restrict__ blockoffs,
    const int* __restrict__ buckbase, unsigned* __restrict__ staging,
    const unsigned short* __restrict__ Xb16, const unsigned short* __restrict__ Bt1,
    unsigned short* __restrict__ Xf, unsigned short* __restrict__ Xb)
{
  __shared__ union {
    int cur[2 * NBUCK];
    struct { unsigned short As[128 * LDA]; unsigned short Bs[128 * LDA]; } mm;
  } sm;
  const int tid = threadIdx.x;
  if (blockIdx.x < NBLK) {
    const int blk = blockIdx.x;
    for (int i = tid; i < 2 * NBUCK; i += 256) {
      int dir = (i >= NBUCK) ? 1 : 0;
      int b = i - dir * NBUCK;
      sm.cur[i] = blockoffs[i * NBLK + blk] + buckbase[dir * (NBUCK + 1) + b];
    }
    __syncthreads();
    unsigned* st0 = staging;
    unsigned* st1 = staging + N_EDGES;
    const int e0 = blk * CHUNK;
    for (int e = e0 + tid; e < e0 + CHUNK; e += 256) {
      int s = ei[e];
      int d = ei[N_EDGES + e];
      int p = atomicAdd(&sm.cur[d >> BSH], 1);
      st0[p] = ((unsigned)(d & (NPB - 1)) << 16) | (unsigned)s;
      int q = atomicAdd(&sm.cur[NBUCK + (s >> BSH)], 1);
      st1[q] = ((unsigned)(s & (NPB - 1)) << 16) | (unsigned)d;
    }
    return;
  }
  const int bid = blockIdx.x - NBLK;
  mm_body(Xb16, N_NODES, Bt1, Xf, Xb, nullptr, 0,
          nullptr, nullptr, nullptr, nullptr, nullptr,
          (bid >> 1) * 128, (bid & 1) * 128, sm.mm.As, sm.mm.Bs);
}

// ---------------- fused: bin-within-bucket (src-range grouped) + attention scores ----
// Counting sort key extended from node to (node, src>>GSH): each node's adjacency
// list comes out ordered by 16 ascending source-ID groups, so k_agg's sequential
// walk sweeps the X table front-to-back -> co-resident waves share a narrow L2-
// resident band instead of the whole 12.8 MB table.
__global__ __launch_bounds__(512) void k_bin_scores(
    const unsigned* __restrict__ staging, const int* __restrict__ buckbase,
    int* __restrict__ rpf, int* __restrict__ rpb,
    int* __restrict__ adjf, int* __restrict__ adjb,
    const unsigned short* __restrict__ Xf, const unsigned short* __restrict__ Xb,
    const float* __restrict__ asf, const float* __restrict__ adf,
    const float* __restrict__ asb, const float* __restrict__ adb,
    float* __restrict__ ALf, float* __restrict__ ARf,
    float* __restrict__ ALb, float* __restrict__ ARb)
{
  const int tid = threadIdx.x;
  if (blockIdx.x < 2 * NBUCK) {
    const int dir = (blockIdx.x >= NBUCK) ? 1 : 0;
    const int b = blockIdx.x - dir * NBUCK;
    const int node0 = b << BSH;
    const int nn = min(NPB, N_NODES - node0);
    const unsigned* st = staging + (size_t)dir * N_EDGES;
    int* rp  = dir ? rpb : rpf;
    int* adj = dir ? adjb : adjf;
    const int beg = buckbase[dir * (NBUCK + 1) + b];
    const int end = buckbase[dir * (NBUCK + 1) + b + 1];

    __shared__ int cnt[NPB * GPAD];   // [node][group], padded stride 17
    __shared__ int wpart[8];
    for (int i = tid; i < NPB * GPAD; i += 512) cnt[i] = 0;
    __syncthreads();
    for (int jj = beg + tid; jj < end; jj += 512) {
      unsigned rec = st[jj];
      atomicAdd(&cnt[(rec >> 16) * GPAD + ((rec & 0xFFFFu) >> GSH)], 1);
    }
    __syncthreads();
    int csub[NGRP];
    int deg1 = 0;
    if (tid < nn) {
      deg1 = 1;                                       // +1 self loop
#pragma unroll
      for (int g = 0; g < NGRP; ++g) { csub[g] = cnt[tid * GPAD + g]; deg1 += csub[g]; }
    }
    int v = deg1;
    const int wl = tid & 63;
#pragma unroll
    for (int off = 1; off < 64; off <<= 1) {
      int u = __shfl_up(v, off, 64);
      if (wl >= off) v += u;
    }
    if (wl == 63) wpart[tid >> 6] = v;
    __syncthreads();
    int pre = 0;
#pragma unroll
    for (int w = 0; w < 7; ++w)
      if (w < (tid >> 6)) pre += wpart[w];
    const int excl = v + pre - deg1;
    if (tid < nn) {
      int r = beg + node0 + excl;
      rp[node0 + tid] = r;
      adj[r] = node0 + tid;                           // self loop first
      int run = r + 1;                                // group sub-bases, ascending src
#pragma unroll
      for (int g = 0; g < NGRP; ++g) { int c = csub[g]; cnt[tid * GPAD + g] = run; run += c; }
    }
    __syncthreads();
    for (int jj = beg + tid; jj < end; jj += 512) {
      unsigned rec = st[jj];
      int p = atomicAdd(&cnt[(rec >> 16) * GPAD + ((rec & 0xFFFFu) >> GSH)], 1);
      adj[p] = (int)(rec & 0xFFFFu);
    }
    return;
  }
  // ---- scores: 8 nodes per block (one wave each), outputs pre-scaled by log2e ----
  const int wave = tid >> 6, lane = tid & 63;
  const int n = (blockIdx.x - 2 * NBUCK) * 8 + wave;
  const int hh = lane >> 5;
  const int c = lane & 31;
  float v0 = bflo((unsigned)Xf[(size_t)n * 128 + lane]);
  float v1 = bflo((unsigned)Xf[(size_t)n * 128 + 64 + lane]);
  float v2 = bflo((unsigned)Xb[(size_t)n * 128 + lane]);
  float v3 = bflo((unsigned)Xb[(size_t)n * 128 + 64 + lane]);
  float s0 = v0 * asf[hh * 32 + c],       d0 = v0 * adf[hh * 32 + c];
  float s1 = v1 * asf[(2 + hh) * 32 + c], d1 = v1 * adf[(2 + hh) * 32 + c];
  float s2 = v2 * asb[hh * 32 + c],       d2 = v2 * adb[hh * 32 + c];
  float s3 = v3 * asb[(2 + hh) * 32 + c], d3 = v3 * adb[(2 + hh) * 32 + c];
#pragma unroll
  for (int off = 16; off > 0; off >>= 1) {
    s0 += __shfl_xor(s0, off, 32); d0 += __shfl_xor(d0, off, 32);
    s1 += __shfl_xor(s1, off, 32); d1 += __shfl_xor(d1, off, 32);
    s2 += __shfl_xor(s2, off, 32); d2 += __shfl_xor(d2, off, 32);
    s3 += __shfl_xor(s3, off, 32); d3 += __shfl_xor(d3, off, 32);
  }
  if (c == 0) {
    ALf[n * 4 + hh] = s0 * LOG2E;     ARf[n * 4 + hh] = d0 * LOG2E;
    ALf[n * 4 + 2 + hh] = s1 * LOG2E; ARf[n * 4 + 2 + hh] = d1 * LOG2E;
    ALb[n * 4 + hh] = s2 * LOG2E;     ARb[n * 4 + hh] = d2 * LOG2E;
    ALb[n * 4 + 2 + hh] = s3 * LOG2E; ARb[n * 4 + 2 + hh] = d3 * LOG2E;
  }
}

// ---------------- fused softmax + aggregation (v4: LDS batch + depth-2 pipeline) ------
// Adjacency lists now arrive src-range-grouped (ascending), so the sequential walk
// below sweeps the X table monotonically -> cross-wave temporal locality in L2.
__global__ __launch_bounds__(256) void k_agg(
    const uint4* __restrict__ Xf, const uint4* __restrict__ Xb,
    const int* __restrict__ rpf, const int* __restrict__ adjf,
    const int* __restrict__ rpb, const int* __restrict__ adjb,
    const float* __restrict__ ALf, const float* __restrict__ ARf,
    const float* __restrict__ ALb, const float* __restrict__ ARb,
    const float* __restrict__ bf, const float* __restrict__ bb,
    unsigned* __restrict__ H16)
{
  __shared__ int      sNB[4][72];
  __shared__ unsigned sW[4][72][2];
  const int dir = blockIdx.y;
  const int wv = threadIdx.x >> 6;
  const int n = blockIdx.x * 4 + wv;
  const uint4* X = dir ? Xb : Xf;
  const int* rp  = dir ? rpb : rpf;
  const int* adj = dir ? adjb : adjf;
  const float* AL = dir ? ALb : ALf;
  const float* AR = dir ? ARb : ARf;
  const float* bias = dir ? bb : bf;
  const int lane = threadIdx.x & 63;
  const int sg = lane >> 4;           // sub-group = which pair-slot of the octet
  const unsigned l = (unsigned)(lane & 15);
  const unsigned h = l >> 2;          // head for channels 8l..8l+7
  const unsigned sel = (h & 1) ? PSEL_HI : PSEL_LO;  // pick this head's half of W[h>>1]
  const float4 ar4 = *(const float4*)(AR + ((size_t)(unsigned)n << 2));
  const int beg = rp[n], end = rp[n + 1];
  const int cntE = end - beg;

  float a[8] = {0.f, 0.f, 0.f, 0.f, 0.f, 0.f, 0.f, 0.f};
  float den = 0.f;

  for (int wb = 0; wb < cntE; wb += 64) {
    const int wcnt = min(cntE - wb, 64);
    // ---- batch phase: one edge per lane -> weights + nb into wave-private LDS ----
    const bool valid = lane < wcnt;
    const int eidx = beg + (valid ? wb + lane : 0);   // beg always valid (self loop)
    const int nb = adj[eidx];
    const float4 alv = *(const float4*)(AL + ((size_t)(unsigned)nb << 2));
    float s0 = alv.x + ar4.x, s1 = alv.y + ar4.y;
    float s2 = alv.z + ar4.z, s3 = alv.w + ar4.w;
    float w0 = fexp2(fmaxf(s0, s0 * NEG_SLOPE));
    float w1 = fexp2(fmaxf(s1, s1 * NEG_SLOPE));
    float w2 = fexp2(fmaxf(s2, s2 * NEG_SLOPE));
    float w3 = fexp2(fmaxf(s3, s3 * NEG_SLOPE));
    // W0 = {lo: bf(w_h0), hi: bf(w_h1)}, W1 = {lo: bf(w_h2), hi: bf(w_h3)}
    unsigned W0 = __builtin_amdgcn_perm(rnebits(w1), rnebits(w0), PSEL_HI);
    unsigned W1 = __builtin_amdgcn_perm(rnebits(w3), rnebits(w2), PSEL_HI);
    if (!valid) { W0 = 0u; W1 = 0u; }   // OOB slots contribute 0 (replaces remainder path)
    sNB[wv][lane] = nb;
    sW[wv][lane][0] = W0;
    sW[wv][lane][1] = W1;
    if (lane < 8) {                     // pad slots 64..71: valid node, zero weight
      sNB[wv][64 + lane] = nb;
      sW[wv][64 + lane][0] = 0u;
      sW[wv][64 + lane][1] = 0u;
    }
    __builtin_amdgcn_wave_barrier();    // intra-wave LDS write->read ordering fence
    // ---- accumulate phase: depth-2 pipelined round-robin pairs ----
    const int K = (wcnt + 7) >> 3;
    {
      const int p0 = 2 * sg;
      int nb0 = sNB[wv][p0];
      int nb1 = sNB[wv][p0 + 1];
      unsigned We0 = sW[wv][p0][h >> 1];
      unsigned We1 = sW[wv][p0 + 1][h >> 1];
      uint4 c0 = X[((unsigned)nb0 << 4) | l];
      uint4 c1 = X[((unsigned)nb1 << 4) | l];
      unsigned wcur = __builtin_amdgcn_perm(We1, We0, sel);
#pragma unroll 2
      for (int k = 0; k < K; ++k) {
        const int pn = 8 * (k + 1) + 2 * sg;          // ≤ 71: covered by pad slots
        const int m0 = sNB[wv][pn];
        const int m1 = sNB[wv][pn + 1];
        const unsigned Vn0 = sW[wv][pn][h >> 1];
        const unsigned Vn1 = sW[wv][pn + 1][h >> 1];
        uint4 n0 = X[((unsigned)m0 << 4) | l];        // issue k+1 before consuming k
        uint4 n1 = X[((unsigned)m1 << 4) | l];
        const unsigned wnext = __builtin_amdgcn_perm(Vn1, Vn0, sel);
        agg_pair(a, den, wcur, c0, c1);
        c0 = n0; c1 = n1; wcur = wnext;
      }
    }
    __builtin_amdgcn_wave_barrier();    // keep next window's writes below these reads
  }
  // reduce across the 4 sub-groups (xor 16, then 32)
#pragma unroll
  for (int off = 16; off <= 32; off <<= 1) {
#pragma unroll
    for (int k = 0; k < 8; ++k) a[k] += __shfl_xor(a[k], off);
    den += __shfl_xor(den, off);
  }
  if (lane < 16) {
    float inv = 1.f / (den + 1e-16f);
    float4 b0 = *(const float4*)(bias + 8 * l);
    float4 b1 = *(const float4*)(bias + 8 * l + 4);
    float v0 = a[0] * inv + b0.x, v1 = a[1] * inv + b0.y;
    float v2 = a[2] * inv + b0.z, v3 = a[3] * inv + b0.w;
    float v4 = a[4] * inv + b1.x, v5 = a[5] * inv + b1.y;
    float v6 = a[6] * inv + b1.z, v7 = a[7] * inv + b1.w;
    uint4 hw;
    hw.x = ((unsigned)f2bf(v1) << 16) | f2bf(v0);
    hw.y = ((unsigned)f2bf(v3) << 16) | f2bf(v2);
    hw.z = ((unsigned)f2bf(v5) << 16) | f2bf(v4);
    hw.w = ((unsigned)f2bf(v7) << 16) | f2bf(v6);
    *(uint4*)(H16 + (unsigned)n * 128u + (unsigned)dir * 64u + 4u * l) = hw;
  }
}

// ---------------- standalone fusion GEMM (mode 1) ----------------
__global__ __launch_bounds__(256) void k_mm2(
    const unsigned short* __restrict__ A, const unsigned short* __restrict__ Bt,
    float* __restrict__ Df,
    const float* __restrict__ bias, const float* __restrict__ gamma,
    const float* __restrict__ beta, const float* __restrict__ mean,
    const float* __restrict__ var)
{
  __shared__ __align__(16) unsigned short As[128 * LDA];
  __shared__ __align__(16) unsigned short Bs[128 * LDA];
  mm_body(A, N_NODES, Bt, nullptr, nullptr, Df, 1,
          bias, gamma, beta, mean, var,
          blockIdx.x * 128, blockIdx.y * 128, As, Bs);
}

// ---------------- launch ----------------

extern "C" void kernel_launch(void* const* d_in, const int* in_sizes, int n_in,
                              void* d_out, int out_size, void* d_ws, size_t ws_size,
                              hipStream_t stream) {
  const float* x    = (const float*)d_in[0];
  const int*   ei   = (const int*)d_in[1];
  const float* W_f  = (const float*)d_in[2];
  const float* asf  = (const float*)d_in[3];
  const float* adf  = (const float*)d_in[4];
  const float* b_f  = (const float*)d_in[5];
  const float* W_b  = (const float*)d_in[6];
  const float* asb  = (const float*)d_in[7];
  const float* adb  = (const float*)d_in[8];
  const float* b_b  = (const float*)d_in[9];
  const float* W_fu = (const float*)d_in[10];
  const float* b_fu = (const float*)d_in[11];
  const float* gam  = (const float*)d_in[12];
  const float* bet  = (const float*)d_in[13];
  const float* mean = (const float*)d_in[14];
  const float* var  = (const float*)d_in[15];
  float* out = (float*)d_out;

  char* base = (char*)d_ws;
  size_t off = 0;
  auto alloc = [&](size_t bytes) {
    void* p = base + off;
    off = (off + bytes + 255) & ~(size_t)255;
    return p;
  };
  // Xb16 (mm1 input) and H16 (agg output / mm2 input) live at disjoint times -> share
  unsigned short* Xb16 = (unsigned short*)alloc((size_t)N_NODES * 256 * 2);
  unsigned* H16        = (unsigned*)Xb16;
  unsigned short* Xf   = (unsigned short*)alloc((size_t)N_NODES * 128 * 2);
  unsigned short* Xb   = (unsigned short*)alloc((size_t)N_NODES * 128 * 2);
  unsigned short* Bt1  = (unsigned short*)alloc((size_t)256 * 256 * 2);
  unsigned short* Bt2  = (unsigned short*)alloc((size_t)256 * 256 * 2);
  float* ALf  = (float*)alloc((size_t)N_NODES * 4 * 4);
  float* ARf  = (float*)alloc((size_t)N_NODES * 4 * 4);
  float* ALb  = (float*)alloc((size_t)N_NODES * 4 * 4);
  float* ARb  = (float*)alloc((size_t)N_NODES * 4 * 4);
  int* rpf    = (int*)alloc((size_t)(N_NODES + 1) * 4);
  int* rpb    = (int*)alloc((size_t)(N_NODES + 1) * 4);
  int* adjf   = (int*)alloc((size_t)(N_EDGES + N_NODES) * 4);
  int* adjb   = (int*)alloc((size_t)(N_EDGES + N_NODES) * 4);
  int* blockhist = (int*)alloc((size_t)2 * NBUCK * NBLK * 4);
  int* blockoffs = (int*)alloc((size_t)2 * NBUCK * NBLK * 4);
  int* bucktotal = (int*)alloc((size_t)2 * NBUCK * 4);
  int* buckbase  = (int*)alloc((size_t)2 * (NBUCK + 1) * 4);
  unsigned* staging = (unsigned*)alloc((size_t)2 * N_EDGES * 4);
  (void)ws_size; (void)in_sizes; (void)n_in; (void)out_size;

  const int XB = (N_NODES * 64) / 256;            // 12500
  const int MB = (N_NODES + 127) / 128;           // 391

  k_setup<<<NBLK + 256 + XB, 256, 0, stream>>>(ei, blockhist, W_f, W_b, W_fu,
                                               Bt1, Bt2, x, Xb16);
  k_rowscan<<<2 * NBUCK, 256, 0, stream>>>(blockhist, blockoffs, bucktotal);
  k_buckscan<<<1, 256, 0, stream>>>(bucktotal, buckbase, rpf, rpb);
  // fused: edge staging (chain A) + projection GEMM (chain B)
  k_stage_mm<<<NBLK + MB * 2, 256, 0, stream>>>(ei, blockoffs, buckbase, staging,
                                                Xb16, Bt1, Xf, Xb);
  // fused: CSR binning (chain A) + attention scores (chain B)
  k_bin_scores<<<2 * NBUCK + N_NODES / 8, 512, 0, stream>>>(
      staging, buckbase, rpf, rpb, adjf, adjb,
      Xf, Xb, asf, adf, asb, adb, ALf, ARf, ALb, ARb);
  k_agg<<<dim3(N_NODES / 4, 2), 256, 0, stream>>>((const uint4*)Xf, (const uint4*)Xb,
                                                  rpf, adjf, rpb, adjb,
                                                  ALf, ARf, ALb, ARb, b_f, b_b, H16);
  k_mm2<<<dim3(MB, 2), 256, 0, stream>>>((const unsigned short*)H16, Bt2, out,
                                         b_fu, gam, bet, mean, var);
}